// Round 3
// baseline (781.601 us; speedup 1.0000x reference)
//
#include <hip/hip_runtime.h>
#include <cstdint>
#include <cstddef>

// ---------------------------------------------------------------------------
// KascadeAnchorAttention: x->QKV proj (+RoPE) -> causal attn -> out proj,
// plus top-8 tile indices from rep-row logits.
// B=2 H=16 S=2048 Dh=128 D=2048. TILE=128 TOPK=8.
//
// Precision plan:
//  - k projection: bf16x2-split MFMA GEMM (fp32-grade) -> fp32 k for scoring
//  - q,v projections + attention + out proj: plain bf16 MFMA (thr=0.3)
//  - scoring: fp32 q_rep recomputed in-kernel; ranking by per-tile max logit
//    (monotone-equivalent to reference softmax+maxpool+top_k, same tie-break)
// k_f32 (33.5MB) is stored in d_out[0..8388607]; scoring runs BEFORE the
// final GEMM overwrites that region.
// Workspace aliasing: obf reuses xh, vtbf reuses xl (dead by then). ~120MiB.
// ---------------------------------------------------------------------------

#define S_LEN 2048
#define NH 16
#define DHD 128
#define DMODEL 2048
#define MROWS 4096
#define SCALE 0.08838834764831845f   // 1/sqrt(128)
#define NEG10 -1e10f

typedef short short8 __attribute__((ext_vector_type(8)));
typedef __bf16 bf16x8 __attribute__((ext_vector_type(8)));
typedef float f32x4 __attribute__((ext_vector_type(4)));

#define MFMA16(a, b, c) __builtin_amdgcn_mfma_f32_16x16x32_bf16((a), (b), (c), 0, 0, 0)

__device__ __forceinline__ void gl16(const void* g, void* s) {
  __builtin_amdgcn_global_load_lds(
      (const __attribute__((address_space(1))) void*)g,
      (__attribute__((address_space(3))) void*)s, 16, 0, 0);
}

__device__ __forceinline__ unsigned short f2bf(float f) {
  unsigned u = __float_as_uint(f);
  return (unsigned short)((u + 0x7fffu + ((u >> 16) & 1u)) >> 16);  // RNE
}
__device__ __forceinline__ float bf2f(unsigned short h) {
  return __uint_as_float(((unsigned)h) << 16);
}

// ---------------- split x into bf16 hi/lo ----------------
__global__ __launch_bounds__(256) void k_split_x(const float* __restrict__ x,
                                                 unsigned short* __restrict__ xh,
                                                 unsigned short* __restrict__ xl, int n4) {
  int i = blockIdx.x * blockDim.x + threadIdx.x;
  for (; i < n4; i += gridDim.x * blockDim.x) {
    float4 v = ((const float4*)x)[i];
    float f[4] = {v.x, v.y, v.z, v.w};
    unsigned short hh[4], ll[4];
#pragma unroll
    for (int j = 0; j < 4; j++) {
      hh[j] = f2bf(f[j]);
      ll[j] = f2bf(f[j] - bf2f(hh[j]));
    }
    ((ushort4*)xh)[i] = make_ushort4(hh[0], hh[1], hh[2], hh[3]);
    ((ushort4*)xl)[i] = make_ushort4(ll[0], ll[1], ll[2], ll[3]);
  }
}

// ---------------- transpose weight [K][N] -> [N][K] bf16 (hi, optional lo) ---
template <int LO>
__global__ __launch_bounds__(256) void k_transw(const float* __restrict__ w,
                                                unsigned short* __restrict__ th,
                                                unsigned short* __restrict__ tl) {
  int n = blockIdx.x * 256 + threadIdx.x;
  int r0 = blockIdx.y * 32;
  float vals[32];
#pragma unroll
  for (int j = 0; j < 32; j++) vals[j] = w[(size_t)(r0 + j) * DMODEL + n];
  unsigned short hs[32];
#pragma unroll
  for (int j = 0; j < 32; j++) hs[j] = f2bf(vals[j]);
  unsigned short* dsth = th + (size_t)n * DMODEL + r0;
#pragma unroll
  for (int c = 0; c < 4; c++) {
    short8 v;
#pragma unroll
    for (int j = 0; j < 8; j++) v[j] = (short)hs[c * 8 + j];
    *(short8*)(dsth + c * 8) = v;
  }
  if (LO) {
    unsigned short ls[32];
#pragma unroll
    for (int j = 0; j < 32; j++) ls[j] = f2bf(vals[j] - bf2f(hs[j]));
    unsigned short* dstl = tl + (size_t)n * DMODEL + r0;
#pragma unroll
    for (int c = 0; c < 4; c++) {
      short8 v;
#pragma unroll
      for (int j = 0; j < 8; j++) v[j] = (short)ls[c * 8 + j];
      *(short8*)(dstl + c * 8) = v;
    }
  }
}

// ---------------- 128x128 MFMA GEMM, BK=32, optional bf16x2 split ----------
// A [4096][2048] bf16 row-major (hi, optional lo); Bt [N][K] bf16 (B^T).
// EPI: 0 -> bf16 store to [B,H,S,Dh]; 1 -> f32 store to [B,H,S,Dh];
//      2 -> f32 store to flat [row][col].
template <int SPLIT, int EPI>
__global__ __launch_bounds__(256) void k_gemm(const unsigned short* __restrict__ A,
                                              const unsigned short* __restrict__ Al,
                                              const unsigned short* __restrict__ Bt,
                                              const unsigned short* __restrict__ Btl,
                                              void* __restrict__ outp) {
  constexpr int NSM = (SPLIT ? 4 : 2) * 4096;
  __shared__ unsigned short sm[NSM];
  unsigned short* sAh = sm;
  unsigned short* sAl = SPLIT ? (sm + 4096) : nullptr;
  unsigned short* sBh = sm + (SPLIT ? 8192 : 4096);
  unsigned short* sBl = SPLIT ? (sm + 12288) : nullptr;

  const int tid = threadIdx.x;
  const int l = tid & 63, w = tid >> 6;
  const int lr = l & 15, lk = l >> 4;
  const int rowBase = blockIdx.y * 128;
  const int colBase = blockIdx.x * 128;
  const int wr = (w >> 1) * 64, wc = (w & 1) * 64;

  f32x4 zero = {0.f, 0.f, 0.f, 0.f};
  f32x4 acc[4][4];
#pragma unroll
  for (int mi = 0; mi < 4; mi++)
#pragma unroll
    for (int ni = 0; ni < 4; ni++) acc[mi][ni] = zero;

  for (int kt = 0; kt < 64; ++kt) {
    // stage A/B tiles (128x32 bf16 = 8KB each) via global_load_lds,
    // source pre-swizzled so LDS is XOR-swizzled: slot ^= (row>>1)&3
#pragma unroll
    for (int p = 0; p < 2; ++p) {
      int c = w * 128 + p * 64 + l;
      int row = c >> 2, sl = c & 3;
      int kbl = sl ^ ((row >> 1) & 3);
      size_t srca = (size_t)(rowBase + row) * DMODEL + kt * 32 + kbl * 8;
      gl16(A + srca, (char*)sAh + c * 16);
      if (SPLIT) gl16(Al + srca, (char*)sAl + c * 16);
      size_t srcb = (size_t)(colBase + row) * DMODEL + kt * 32 + kbl * 8;
      gl16(Bt + srcb, (char*)sBh + c * 16);
      if (SPLIT) gl16(Btl + srcb, (char*)sBl + c * 16);
    }
    __syncthreads();

    bf16x8 ah[4], alo[4], bh[4], blo[4];
#pragma unroll
    for (int mi = 0; mi < 4; mi++) {
      int row = wr + mi * 16 + lr;
      int off = row * 32 + ((lk ^ ((row >> 1) & 3)) * 8);
      ah[mi] = *(const bf16x8*)(sAh + off);
      if (SPLIT) alo[mi] = *(const bf16x8*)(sAl + off);
    }
#pragma unroll
    for (int ni = 0; ni < 4; ni++) {
      int row = wc + ni * 16 + lr;
      int off = row * 32 + ((lk ^ ((row >> 1) & 3)) * 8);
      bh[ni] = *(const bf16x8*)(sBh + off);
      if (SPLIT) blo[ni] = *(const bf16x8*)(sBl + off);
    }
#pragma unroll
    for (int mi = 0; mi < 4; mi++)
#pragma unroll
      for (int ni = 0; ni < 4; ni++) {
        acc[mi][ni] = MFMA16(ah[mi], bh[ni], acc[mi][ni]);
        if (SPLIT) {
          acc[mi][ni] = MFMA16(alo[mi], bh[ni], acc[mi][ni]);
          acc[mi][ni] = MFMA16(ah[mi], blo[ni], acc[mi][ni]);
        }
      }
    __syncthreads();
  }

  // epilogue: C row = M-row, col = N-col; frag: col=l&15, row=(l>>4)*4+reg
#pragma unroll
  for (int mi = 0; mi < 4; mi++)
#pragma unroll
    for (int ni = 0; ni < 4; ni++)
#pragma unroll
      for (int r = 0; r < 4; r++) {
        int row = rowBase + wr + mi * 16 + lk * 4 + r;
        int col = colBase + wc + ni * 16 + lr;
        float v = acc[mi][ni][r];
        if (EPI == 2) {
          ((float*)outp)[(size_t)row * DMODEL + col] = v;
        } else {
          size_t idx = (((size_t)(row >> 11) * NH + (col >> 7)) * S_LEN + (row & 2047)) * DHD +
                       (col & 127);
          if (EPI == 1)
            ((float*)outp)[idx] = v;
          else
            ((unsigned short*)outp)[idx] = f2bf(v);
        }
      }
}

// ---------------- RoPE, half-split form -------------------------------------
__global__ __launch_bounds__(256) void k_rope_q(unsigned short* __restrict__ q,
                                                const float* __restrict__ cosT,
                                                const float* __restrict__ sinT) {
  int t = blockIdx.x * blockDim.x + threadIdx.x;  // 32*2048*16 threads
  int row = t >> 4;
  int i4 = (t & 15) * 4;
  int s = row & 2047;
  unsigned short* p0 = q + (size_t)row * DHD + i4;
  unsigned short* p1 = p0 + 64;
  ushort4 a = *(ushort4*)p0, b = *(ushort4*)p1;
  float4 c = *(const float4*)(cosT + (size_t)s * 64 + i4);
  float4 sn = *(const float4*)(sinT + (size_t)s * 64 + i4);
  float av[4] = {bf2f(a.x), bf2f(a.y), bf2f(a.z), bf2f(a.w)};
  float bv[4] = {bf2f(b.x), bf2f(b.y), bf2f(b.z), bf2f(b.w)};
  float cv[4] = {c.x, c.y, c.z, c.w}, sv[4] = {sn.x, sn.y, sn.z, sn.w};
  unsigned short na[4], nb[4];
#pragma unroll
  for (int j = 0; j < 4; j++) {
    na[j] = f2bf(av[j] * cv[j] - bv[j] * sv[j]);
    nb[j] = f2bf(bv[j] * cv[j] + av[j] * sv[j]);
  }
  *(ushort4*)p0 = make_ushort4(na[0], na[1], na[2], na[3]);
  *(ushort4*)p1 = make_ushort4(nb[0], nb[1], nb[2], nb[3]);
}

__global__ __launch_bounds__(256) void k_rope_k(float* __restrict__ kf,
                                                unsigned short* __restrict__ kb,
                                                const float* __restrict__ cosT,
                                                const float* __restrict__ sinT) {
  int t = blockIdx.x * blockDim.x + threadIdx.x;
  int row = t >> 4;
  int i4 = (t & 15) * 4;
  int s = row & 2047;
  float* p0 = kf + (size_t)row * DHD + i4;
  float* p1 = p0 + 64;
  float4 a = *(float4*)p0, b = *(float4*)p1;
  float4 c = *(const float4*)(cosT + (size_t)s * 64 + i4);
  float4 sn = *(const float4*)(sinT + (size_t)s * 64 + i4);
  float av[4] = {a.x, a.y, a.z, a.w}, bv[4] = {b.x, b.y, b.z, b.w};
  float cv[4] = {c.x, c.y, c.z, c.w}, sv[4] = {sn.x, sn.y, sn.z, sn.w};
  float na[4], nb[4];
#pragma unroll
  for (int j = 0; j < 4; j++) {
    na[j] = av[j] * cv[j] - bv[j] * sv[j];
    nb[j] = bv[j] * cv[j] + av[j] * sv[j];
  }
  *(float4*)p0 = make_float4(na[0], na[1], na[2], na[3]);
  *(float4*)p1 = make_float4(nb[0], nb[1], nb[2], nb[3]);
  unsigned short* kb0 = kb + (size_t)row * DHD + i4;
  *(ushort4*)kb0 = make_ushort4(f2bf(na[0]), f2bf(na[1]), f2bf(na[2]), f2bf(na[3]));
  *(ushort4*)(kb0 + 64) = make_ushort4(f2bf(nb[0]), f2bf(nb[1]), f2bf(nb[2]), f2bf(nb[3]));
}

// ---------------- V transpose: [bh][S][Dh] -> [bh][Dh][S] bf16 --------------
__global__ __launch_bounds__(256) void k_vtrans(const unsigned short* __restrict__ v,
                                                unsigned short* __restrict__ vt) {
  int bh = blockIdx.y;
  int s0 = blockIdx.x * 64 + (threadIdx.x >> 7) * 32;
  int d = threadIdx.x & 127;
  unsigned short tmp[32];
#pragma unroll
  for (int j = 0; j < 32; j++) tmp[j] = v[((size_t)bh * S_LEN + s0 + j) * DHD + d];
  unsigned short* dst = vt + ((size_t)bh * DHD + d) * S_LEN + s0;
#pragma unroll
  for (int c = 0; c < 4; c++) {
    short8 x;
#pragma unroll
    for (int j = 0; j < 8; j++) x[j] = (short)tmp[c * 8 + j];
    *(short8*)(dst + c * 8) = x;
  }
}

// ---------------- flash attention (causal), 128q-tile, 64k-tiles ------------
__global__ __launch_bounds__(256) void k_attn(const unsigned short* __restrict__ q,
                                              const unsigned short* __restrict__ k,
                                              const unsigned short* __restrict__ vt,
                                              unsigned short* __restrict__ o) {
  __shared__ unsigned short sK[64 * 128];  // [kp][d], slot^=(kp&7) swizzle
  __shared__ unsigned short sV[128 * 64];  // [dh][kp], slot^=(dh&7) swizzle
  __shared__ unsigned short sP[128 * 72];  // [qrow][kcol], +8 pad
  const int qt = blockIdx.x, bh = blockIdx.y;
  const int b = bh >> 4, h = bh & 15;
  const int tid = threadIdx.x, l = tid & 63, w = tid >> 6;
  const int lr = l & 15, lk = l >> 4;
  const int q0 = qt * 128;
  const size_t kvbase = (size_t)bh * S_LEN * DHD;

  bf16x8 qf[2][4];
#pragma unroll
  for (int mi = 0; mi < 2; mi++)
#pragma unroll
    for (int kd = 0; kd < 4; kd++) {
      int row = q0 + w * 32 + mi * 16 + lr;
      qf[mi][kd] = *(const bf16x8*)(q + kvbase + (size_t)row * DHD + kd * 32 + lk * 8);
    }

  f32x4 zero = {0.f, 0.f, 0.f, 0.f};
  f32x4 acc[2][8];
#pragma unroll
  for (int mi = 0; mi < 2; mi++)
#pragma unroll
    for (int ni = 0; ni < 8; ni++) acc[mi][ni] = zero;
  float mrow[2][4], lsum[2][4];
#pragma unroll
  for (int mi = 0; mi < 2; mi++)
#pragma unroll
    for (int r = 0; r < 4; r++) {
      mrow[mi][r] = -3e38f;
      lsum[mi][r] = 0.f;
    }

  const int nkt = 2 * qt + 2;
  for (int kt = 0; kt < nkt; ++kt) {
    // stage K tile 64x128 (16KB, 1024 chunks) and V^T tile 128x64 (16KB)
#pragma unroll
    for (int p = 0; p < 4; ++p) {
      int c = p * 256 + w * 64 + l;
      int kp = c >> 4, sl = c & 15;
      int sls = sl ^ (kp & 7);
      gl16(k + kvbase + (size_t)(kt * 64 + kp) * DHD + sls * 8, (char*)sK + c * 16);
    }
#pragma unroll
    for (int p = 0; p < 4; ++p) {
      int c = p * 256 + w * 64 + l;
      int dh = c >> 3, sl = c & 7;
      int sls = sl ^ (dh & 7);
      gl16(vt + ((size_t)bh * DHD + dh) * S_LEN + kt * 64 + sls * 8, (char*)sV + c * 16);
    }
    __syncthreads();

    // QK^T -> S frags
    f32x4 sf[2][4];
#pragma unroll
    for (int mi = 0; mi < 2; mi++)
#pragma unroll
      for (int nk = 0; nk < 4; nk++) {
        f32x4 sacc = zero;
#pragma unroll
        for (int kd = 0; kd < 4; kd++) {
          int row = nk * 16 + lr;
          int off = row * 128 + (((kd * 4 + lk) ^ (row & 7)) * 8);
          bf16x8 kf = *(const bf16x8*)(sK + off);
          sacc = MFMA16(qf[mi][kd], kf, sacc);
        }
        sf[mi][nk] = sacc;
      }

    // online softmax + write P (bf16) to LDS
#pragma unroll
    for (int mi = 0; mi < 2; mi++) {
#pragma unroll
      for (int r = 0; r < 4; r++) {
        int qpos = q0 + w * 32 + mi * 16 + lk * 4 + r;
        float lg[4];
        float mx = -3e38f;
#pragma unroll
        for (int nk = 0; nk < 4; nk++) {
          int kpos = kt * 64 + nk * 16 + lr;
          float vsc = sf[mi][nk][r] * SCALE;
          if (kpos > qpos) vsc = -3e38f;
          lg[nk] = vsc;
          mx = fmaxf(mx, vsc);
        }
#pragma unroll
        for (int d = 1; d < 16; d <<= 1) mx = fmaxf(mx, __shfl_xor(mx, d));
        float mnew = fmaxf(mrow[mi][r], mx);
        float corr = expf(mrow[mi][r] - mnew);
        float ps = 0.f;
        unsigned short pb[4];
#pragma unroll
        for (int nk = 0; nk < 4; nk++) {
          float p = expf(lg[nk] - mnew);
          ps += p;
          pb[nk] = f2bf(p);
        }
#pragma unroll
        for (int d = 1; d < 16; d <<= 1) ps += __shfl_xor(ps, d);
        lsum[mi][r] = lsum[mi][r] * corr + ps;
        mrow[mi][r] = mnew;
#pragma unroll
        for (int ni = 0; ni < 8; ni++) acc[mi][ni][r] *= corr;
        int prow = w * 32 + mi * 16 + lk * 4 + r;
#pragma unroll
        for (int nk = 0; nk < 4; nk++) sP[prow * 72 + nk * 16 + lr] = pb[nk];
      }
    }
    __syncthreads();

    // PV: O += P @ V
    bf16x8 pa[2][2];
#pragma unroll
    for (int mi = 0; mi < 2; mi++)
#pragma unroll
      for (int ks = 0; ks < 2; ks++) {
        int row = w * 32 + mi * 16 + lr;
        pa[mi][ks] = *(const bf16x8*)(sP + row * 72 + ks * 32 + lk * 8);
      }
#pragma unroll
    for (int ni = 0; ni < 8; ni++) {
#pragma unroll
      for (int ks = 0; ks < 2; ks++) {
        int row = ni * 16 + lr;
        int off = row * 64 + (((ks * 4 + lk) ^ (row & 7)) * 8);
        bf16x8 vf = *(const bf16x8*)(sV + off);
#pragma unroll
        for (int mi = 0; mi < 2; mi++) acc[mi][ni] = MFMA16(pa[mi][ks], vf, acc[mi][ni]);
      }
    }
    __syncthreads();
  }

  // normalize + store O as bf16 into [B][S][H*Dh]
#pragma unroll
  for (int mi = 0; mi < 2; mi++)
#pragma unroll
    for (int r = 0; r < 4; r++) {
      float inv = 1.0f / lsum[mi][r];
      int srow = q0 + w * 32 + mi * 16 + lk * 4 + r;
      size_t base = ((size_t)b * S_LEN + srow) * DMODEL + h * DHD;
#pragma unroll
      for (int ni = 0; ni < 8; ni++) o[base + ni * 16 + lr] = f2bf(acc[mi][ni][r] * inv);
    }
}

// ---------------- tile scoring + top-8 (exact ranking, fp32) ----------------
__global__ __launch_bounds__(256) void k_score(const float* __restrict__ x,
                                               const float* __restrict__ wq,
                                               const float* __restrict__ cosT,
                                               const float* __restrict__ sinT,
                                               const float* __restrict__ kf,
                                               float* __restrict__ idxout) {
  const int t = blockIdx.x, bh = blockIdx.y;
  const int b = bh >> 4, h = bh & 15;
  const int srep = t * 128 + 127;
  const int tid = threadIdx.x;
  __shared__ float qr[128];
  __shared__ float part[256];
  __shared__ unsigned keys[16];

  // q_rep = x[b,srep,:] @ wq[:, h*128 .. +127], fp32
  {
    const int dh = tid & 127, half = tid >> 7;
    const float* xrow = x + ((size_t)b * S_LEN + srep) * DMODEL;
    const float* wcol = wq + (size_t)h * DHD + dh;
    float s0 = 0.f, s1 = 0.f, s2 = 0.f, s3 = 0.f;
    const int dbase = half * 1024;
    for (int d = 0; d < 1024; d += 4) {
      int dd = dbase + d;
      s0 = fmaf(xrow[dd], wcol[(size_t)dd * DMODEL], s0);
      s1 = fmaf(xrow[dd + 1], wcol[(size_t)(dd + 1) * DMODEL], s1);
      s2 = fmaf(xrow[dd + 2], wcol[(size_t)(dd + 2) * DMODEL], s2);
      s3 = fmaf(xrow[dd + 3], wcol[(size_t)(dd + 3) * DMODEL], s3);
    }
    part[tid] = (s0 + s1) + (s2 + s3);
  }
  if (tid < 16) keys[tid] = ~__float_as_uint(NEG10);  // enc(-1e10), negative => ~u
  __syncthreads();
  if (tid < 64) {
    int i = tid;
    float q0v = part[i] + part[i + 128];
    float q1v = part[i + 64] + part[i + 192];
    float c = cosT[(size_t)srep * 64 + i], sn = sinT[(size_t)srep * 64 + i];
    qr[i] = q0v * c - q1v * sn;
    qr[i + 64] = q1v * c + q0v * sn;
  }
  __syncthreads();

  // per-tile max logit over j <= srep (ranking-equivalent to softmax+maxpool)
  for (int j = tid; j <= srep; j += 256) {
    const float4* krow = (const float4*)(kf + ((size_t)bh * S_LEN + j) * DHD);
    float a0 = 0.f, a1 = 0.f, a2 = 0.f, a3 = 0.f;
#pragma unroll 8
    for (int d4 = 0; d4 < 32; d4++) {
      float4 kv = krow[d4];
      const float* qq = qr + d4 * 4;
      a0 = fmaf(kv.x, qq[0], a0);
      a1 = fmaf(kv.y, qq[1], a1);
      a2 = fmaf(kv.z, qq[2], a2);
      a3 = fmaf(kv.w, qq[3], a3);
    }
    float lg = ((a0 + a1) + (a2 + a3)) * SCALE;
    unsigned u = __float_as_uint(lg);
    unsigned key = (u & 0x80000000u) ? ~u : (u | 0x80000000u);
    atomicMax(&keys[j >> 7], key);
  }
  __syncthreads();

  if (tid == 0) {
    unsigned used = 0;
    float* dst = idxout + ((size_t)bh * 16 + t) * 8;
    for (int r = 0; r < 8; ++r) {
      int best = -1;
      unsigned bk = 0;
#pragma unroll
      for (int tl = 0; tl < 16; ++tl) {
        if (used & (1u << tl)) continue;
        unsigned kv = keys[tl];
        if (best < 0 || kv > bk) {
          bk = kv;
          best = tl;
        }
      }
      used |= (1u << best);
      dst[r] = (float)best;
    }
  }
}

// ---------------------------------------------------------------------------
extern "C" void kernel_launch(void* const* d_in, const int* in_sizes, int n_in,
                              void* d_out, int out_size, void* d_ws, size_t ws_size,
                              hipStream_t stream) {
  (void)in_sizes; (void)n_in; (void)out_size; (void)ws_size;
  const float* x = (const float*)d_in[0];
  const float* wq = (const float*)d_in[1];
  const float* wk = (const float*)d_in[2];
  const float* wv = (const float*)d_in[3];
  const float* wo = (const float*)d_in[4];
  const float* cosT = (const float*)d_in[5];
  const float* sinT = (const float*)d_in[6];
  float* out0 = (float*)d_out;                       // [2,2048,2048] fp32
  float* out1 = out0 + (size_t)MROWS * DMODEL;       // [2,16,16,8] indices as float
  float* kf32 = out0;                                // reuse out0 as k_f32 scratch!

  char* ws = (char*)d_ws;
  size_t off = 0;
  auto alloc = [&](size_t bytes) {
    void* p = ws + off;
    off += (bytes + 255) & ~(size_t)255;
    return p;
  };
  unsigned short* xh = (unsigned short*)alloc(16777216);
  unsigned short* xl = (unsigned short*)alloc(16777216);
  unsigned short* wqT = (unsigned short*)alloc(8388608);
  unsigned short* wkT = (unsigned short*)alloc(8388608);
  unsigned short* wkTl = (unsigned short*)alloc(8388608);
  unsigned short* wvT = (unsigned short*)alloc(8388608);
  unsigned short* woT = (unsigned short*)alloc(8388608);
  unsigned short* qbf = (unsigned short*)alloc(16777216);
  unsigned short* kbf = (unsigned short*)alloc(16777216);
  unsigned short* vbf = (unsigned short*)alloc(16777216);
  // alias dead regions: obf<-xh (xh dead after proj GEMMs), vtbf<-xl
  unsigned short* obf = xh;
  unsigned short* vtbf = xl;
  // total ws use: ~120MiB

  k_split_x<<<2048, 256, 0, stream>>>(x, xh, xl, MROWS * DMODEL / 4);
  dim3 gtw(8, 64);
  k_transw<0><<<gtw, 256, 0, stream>>>(wq, wqT, nullptr);
  k_transw<1><<<gtw, 256, 0, stream>>>(wk, wkT, wkTl);
  k_transw<0><<<gtw, 256, 0, stream>>>(wv, wvT, nullptr);
  k_transw<0><<<gtw, 256, 0, stream>>>(wo, woT, nullptr);

  dim3 gg(16, 32);
  k_gemm<0, 0><<<gg, 256, 0, stream>>>(xh, nullptr, wqT, nullptr, qbf);
  k_gemm<1, 1><<<gg, 256, 0, stream>>>(xh, xl, wkT, wkTl, kf32);   // fp32-grade k
  k_gemm<0, 0><<<gg, 256, 0, stream>>>(xh, nullptr, wvT, nullptr, vbf);

  k_rope_q<<<4096, 256, 0, stream>>>(qbf, cosT, sinT);
  k_rope_k<<<4096, 256, 0, stream>>>(kf32, kbf, cosT, sinT);

  k_vtrans<<<dim3(32, 32), 256, 0, stream>>>(vbf, vtbf);
  k_attn<<<dim3(16, 32), 256, 0, stream>>>(qbf, kbf, vtbf, obf);

  // scoring must run BEFORE the final GEMM overwrites kf32 (== out0)
  k_score<<<dim3(16, 32), 256, 0, stream>>>(x, wq, cosT, sinT, kf32, out1);

  k_gemm<0, 2><<<gg, 256, 0, stream>>>(obf, nullptr, woT, nullptr, out0);
}

// Round 4
// 700.387 us; speedup vs baseline: 1.1160x; 1.1160x over previous
//
#include <hip/hip_runtime.h>
#include <cstdint>
#include <cstddef>

// ---------------------------------------------------------------------------
// KascadeAnchorAttention: x->QKV proj (+RoPE) -> causal attn -> out proj,
// plus top-8 tile indices from rep-row logits.
// B=2 H=16 S=2048 Dh=128 D=2048. TILE=128 TOPK=8.
//
// R3 -> R4: attention reworked for occupancy/balance:
//   QBLK 128->64 (1024 blocks, 41KB LDS, 3 blk/CU), __launch_bounds__(256,3),
//   exp2-domain softmax (v_exp_f32), diagonal-only causal mask.
// Everything else unchanged from the passing R3 kernel.
// ---------------------------------------------------------------------------

#define S_LEN 2048
#define NH 16
#define DHD 128
#define DMODEL 2048
#define MROWS 4096
#define SCALE 0.08838834764831845f   // 1/sqrt(128)
#define SCALE_L2E (0.08838834764831845f * 1.4426950408889634f)
#define NEG10 -1e10f

typedef short short8 __attribute__((ext_vector_type(8)));
typedef __bf16 bf16x8 __attribute__((ext_vector_type(8)));
typedef float f32x4 __attribute__((ext_vector_type(4)));

#define MFMA16(a, b, c) __builtin_amdgcn_mfma_f32_16x16x32_bf16((a), (b), (c), 0, 0, 0)

__device__ __forceinline__ void gl16(const void* g, void* s) {
  __builtin_amdgcn_global_load_lds(
      (const __attribute__((address_space(1))) void*)g,
      (__attribute__((address_space(3))) void*)s, 16, 0, 0);
}

__device__ __forceinline__ unsigned short f2bf(float f) {
  unsigned u = __float_as_uint(f);
  return (unsigned short)((u + 0x7fffu + ((u >> 16) & 1u)) >> 16);  // RNE
}
__device__ __forceinline__ float bf2f(unsigned short h) {
  return __uint_as_float(((unsigned)h) << 16);
}

// ---------------- split x into bf16 hi/lo ----------------
__global__ __launch_bounds__(256) void k_split_x(const float* __restrict__ x,
                                                 unsigned short* __restrict__ xh,
                                                 unsigned short* __restrict__ xl, int n4) {
  int i = blockIdx.x * blockDim.x + threadIdx.x;
  for (; i < n4; i += gridDim.x * blockDim.x) {
    float4 v = ((const float4*)x)[i];
    float f[4] = {v.x, v.y, v.z, v.w};
    unsigned short hh[4], ll[4];
#pragma unroll
    for (int j = 0; j < 4; j++) {
      hh[j] = f2bf(f[j]);
      ll[j] = f2bf(f[j] - bf2f(hh[j]));
    }
    ((ushort4*)xh)[i] = make_ushort4(hh[0], hh[1], hh[2], hh[3]);
    ((ushort4*)xl)[i] = make_ushort4(ll[0], ll[1], ll[2], ll[3]);
  }
}

// ---------------- transpose weight [K][N] -> [N][K] bf16 (hi, optional lo) ---
template <int LO>
__global__ __launch_bounds__(256) void k_transw(const float* __restrict__ w,
                                                unsigned short* __restrict__ th,
                                                unsigned short* __restrict__ tl) {
  int n = blockIdx.x * 256 + threadIdx.x;
  int r0 = blockIdx.y * 32;
  float vals[32];
#pragma unroll
  for (int j = 0; j < 32; j++) vals[j] = w[(size_t)(r0 + j) * DMODEL + n];
  unsigned short hs[32];
#pragma unroll
  for (int j = 0; j < 32; j++) hs[j] = f2bf(vals[j]);
  unsigned short* dsth = th + (size_t)n * DMODEL + r0;
#pragma unroll
  for (int c = 0; c < 4; c++) {
    short8 v;
#pragma unroll
    for (int j = 0; j < 8; j++) v[j] = (short)hs[c * 8 + j];
    *(short8*)(dsth + c * 8) = v;
  }
  if (LO) {
    unsigned short ls[32];
#pragma unroll
    for (int j = 0; j < 32; j++) ls[j] = f2bf(vals[j] - bf2f(hs[j]));
    unsigned short* dstl = tl + (size_t)n * DMODEL + r0;
#pragma unroll
    for (int c = 0; c < 4; c++) {
      short8 v;
#pragma unroll
      for (int j = 0; j < 8; j++) v[j] = (short)ls[c * 8 + j];
      *(short8*)(dstl + c * 8) = v;
    }
  }
}

// ---------------- 128x128 MFMA GEMM, BK=32, optional bf16x2 split ----------
// A [4096][2048] bf16 row-major (hi, optional lo); Bt [N][K] bf16 (B^T).
// EPI: 0 -> bf16 store to [B,H,S,Dh]; 1 -> f32 store to [B,H,S,Dh];
//      2 -> f32 store to flat [row][col].
template <int SPLIT, int EPI>
__global__ __launch_bounds__(256) void k_gemm(const unsigned short* __restrict__ A,
                                              const unsigned short* __restrict__ Al,
                                              const unsigned short* __restrict__ Bt,
                                              const unsigned short* __restrict__ Btl,
                                              void* __restrict__ outp) {
  constexpr int NSM = (SPLIT ? 4 : 2) * 4096;
  __shared__ unsigned short sm[NSM];
  unsigned short* sAh = sm;
  unsigned short* sAl = SPLIT ? (sm + 4096) : nullptr;
  unsigned short* sBh = sm + (SPLIT ? 8192 : 4096);
  unsigned short* sBl = SPLIT ? (sm + 12288) : nullptr;

  const int tid = threadIdx.x;
  const int l = tid & 63, w = tid >> 6;
  const int lr = l & 15, lk = l >> 4;
  const int rowBase = blockIdx.y * 128;
  const int colBase = blockIdx.x * 128;
  const int wr = (w >> 1) * 64, wc = (w & 1) * 64;

  f32x4 zero = {0.f, 0.f, 0.f, 0.f};
  f32x4 acc[4][4];
#pragma unroll
  for (int mi = 0; mi < 4; mi++)
#pragma unroll
    for (int ni = 0; ni < 4; ni++) acc[mi][ni] = zero;

  for (int kt = 0; kt < 64; ++kt) {
#pragma unroll
    for (int p = 0; p < 2; ++p) {
      int c = w * 128 + p * 64 + l;
      int row = c >> 2, sl = c & 3;
      int kbl = sl ^ ((row >> 1) & 3);
      size_t srca = (size_t)(rowBase + row) * DMODEL + kt * 32 + kbl * 8;
      gl16(A + srca, (char*)sAh + c * 16);
      if (SPLIT) gl16(Al + srca, (char*)sAl + c * 16);
      size_t srcb = (size_t)(colBase + row) * DMODEL + kt * 32 + kbl * 8;
      gl16(Bt + srcb, (char*)sBh + c * 16);
      if (SPLIT) gl16(Btl + srcb, (char*)sBl + c * 16);
    }
    __syncthreads();

    bf16x8 ah[4], alo[4], bh[4], blo[4];
#pragma unroll
    for (int mi = 0; mi < 4; mi++) {
      int row = wr + mi * 16 + lr;
      int off = row * 32 + ((lk ^ ((row >> 1) & 3)) * 8);
      ah[mi] = *(const bf16x8*)(sAh + off);
      if (SPLIT) alo[mi] = *(const bf16x8*)(sAl + off);
    }
#pragma unroll
    for (int ni = 0; ni < 4; ni++) {
      int row = wc + ni * 16 + lr;
      int off = row * 32 + ((lk ^ ((row >> 1) & 3)) * 8);
      bh[ni] = *(const bf16x8*)(sBh + off);
      if (SPLIT) blo[ni] = *(const bf16x8*)(sBl + off);
    }
#pragma unroll
    for (int mi = 0; mi < 4; mi++)
#pragma unroll
      for (int ni = 0; ni < 4; ni++) {
        acc[mi][ni] = MFMA16(ah[mi], bh[ni], acc[mi][ni]);
        if (SPLIT) {
          acc[mi][ni] = MFMA16(alo[mi], bh[ni], acc[mi][ni]);
          acc[mi][ni] = MFMA16(ah[mi], blo[ni], acc[mi][ni]);
        }
      }
    __syncthreads();
  }

#pragma unroll
  for (int mi = 0; mi < 4; mi++)
#pragma unroll
    for (int ni = 0; ni < 4; ni++)
#pragma unroll
      for (int r = 0; r < 4; r++) {
        int row = rowBase + wr + mi * 16 + lk * 4 + r;
        int col = colBase + wc + ni * 16 + lr;
        float v = acc[mi][ni][r];
        if (EPI == 2) {
          ((float*)outp)[(size_t)row * DMODEL + col] = v;
        } else {
          size_t idx = (((size_t)(row >> 11) * NH + (col >> 7)) * S_LEN + (row & 2047)) * DHD +
                       (col & 127);
          if (EPI == 1)
            ((float*)outp)[idx] = v;
          else
            ((unsigned short*)outp)[idx] = f2bf(v);
        }
      }
}

// ---------------- RoPE, half-split form -------------------------------------
__global__ __launch_bounds__(256) void k_rope_q(unsigned short* __restrict__ q,
                                                const float* __restrict__ cosT,
                                                const float* __restrict__ sinT) {
  int t = blockIdx.x * blockDim.x + threadIdx.x;
  int row = t >> 4;
  int i4 = (t & 15) * 4;
  int s = row & 2047;
  unsigned short* p0 = q + (size_t)row * DHD + i4;
  unsigned short* p1 = p0 + 64;
  ushort4 a = *(ushort4*)p0, b = *(ushort4*)p1;
  float4 c = *(const float4*)(cosT + (size_t)s * 64 + i4);
  float4 sn = *(const float4*)(sinT + (size_t)s * 64 + i4);
  float av[4] = {bf2f(a.x), bf2f(a.y), bf2f(a.z), bf2f(a.w)};
  float bv[4] = {bf2f(b.x), bf2f(b.y), bf2f(b.z), bf2f(b.w)};
  float cv[4] = {c.x, c.y, c.z, c.w}, sv[4] = {sn.x, sn.y, sn.z, sn.w};
  unsigned short na[4], nb[4];
#pragma unroll
  for (int j = 0; j < 4; j++) {
    na[j] = f2bf(av[j] * cv[j] - bv[j] * sv[j]);
    nb[j] = f2bf(bv[j] * cv[j] + av[j] * sv[j]);
  }
  *(ushort4*)p0 = make_ushort4(na[0], na[1], na[2], na[3]);
  *(ushort4*)p1 = make_ushort4(nb[0], nb[1], nb[2], nb[3]);
}

__global__ __launch_bounds__(256) void k_rope_k(float* __restrict__ kf,
                                                unsigned short* __restrict__ kb,
                                                const float* __restrict__ cosT,
                                                const float* __restrict__ sinT) {
  int t = blockIdx.x * blockDim.x + threadIdx.x;
  int row = t >> 4;
  int i4 = (t & 15) * 4;
  int s = row & 2047;
  float* p0 = kf + (size_t)row * DHD + i4;
  float* p1 = p0 + 64;
  float4 a = *(float4*)p0, b = *(float4*)p1;
  float4 c = *(const float4*)(cosT + (size_t)s * 64 + i4);
  float4 sn = *(const float4*)(sinT + (size_t)s * 64 + i4);
  float av[4] = {a.x, a.y, a.z, a.w}, bv[4] = {b.x, b.y, b.z, b.w};
  float cv[4] = {c.x, c.y, c.z, c.w}, sv[4] = {sn.x, sn.y, sn.z, sn.w};
  float na[4], nb[4];
#pragma unroll
  for (int j = 0; j < 4; j++) {
    na[j] = av[j] * cv[j] - bv[j] * sv[j];
    nb[j] = bv[j] * cv[j] + av[j] * sv[j];
  }
  *(float4*)p0 = make_float4(na[0], na[1], na[2], na[3]);
  *(float4*)p1 = make_float4(nb[0], nb[1], nb[2], nb[3]);
  unsigned short* kb0 = kb + (size_t)row * DHD + i4;
  *(ushort4*)kb0 = make_ushort4(f2bf(na[0]), f2bf(na[1]), f2bf(na[2]), f2bf(na[3]));
  *(ushort4*)(kb0 + 64) = make_ushort4(f2bf(nb[0]), f2bf(nb[1]), f2bf(nb[2]), f2bf(nb[3]));
}

// ---------------- V transpose: [bh][S][Dh] -> [bh][Dh][S] bf16 --------------
__global__ __launch_bounds__(256) void k_vtrans(const unsigned short* __restrict__ v,
                                                unsigned short* __restrict__ vt) {
  int bh = blockIdx.y;
  int s0 = blockIdx.x * 64 + (threadIdx.x >> 7) * 32;
  int d = threadIdx.x & 127;
  unsigned short tmp[32];
#pragma unroll
  for (int j = 0; j < 32; j++) tmp[j] = v[((size_t)bh * S_LEN + s0 + j) * DHD + d];
  unsigned short* dst = vt + ((size_t)bh * DHD + d) * S_LEN + s0;
#pragma unroll
  for (int c = 0; c < 4; c++) {
    short8 x;
#pragma unroll
    for (int j = 0; j < 8; j++) x[j] = (short)tmp[c * 8 + j];
    *(short8*)(dst + c * 8) = x;
  }
}

// ---------------- flash attention (causal), 64q-tile, 64k-tiles -------------
// 1024 blocks (32 qt x 32 bh), 256 thr / 4 waves, each wave owns 16 q-rows.
// LDS 41.2KB -> 3 blocks/CU; launch_bounds(256,3) caps VGPR for 3 waves/SIMD.
__global__ __launch_bounds__(256, 3) void k_attn(const unsigned short* __restrict__ q,
                                                 const unsigned short* __restrict__ k,
                                                 const unsigned short* __restrict__ vt,
                                                 unsigned short* __restrict__ o) {
  __shared__ unsigned short sK[64 * 128];  // [kp][d], 16B-slot ^= (kp&7)
  __shared__ unsigned short sV[128 * 64];  // [dh][kp], 16B-slot ^= (dh&7)
  __shared__ unsigned short sP[64 * 72];   // [qrow][kcol], +8 pad
  const int qt = blockIdx.x, bh = blockIdx.y;
  const int b = bh >> 4, h = bh & 15;
  const int tid = threadIdx.x, l = tid & 63, w = tid >> 6;
  const int lr = l & 15, lk = l >> 4;
  const int q0 = qt * 64;
  const size_t kvbase = (size_t)bh * S_LEN * DHD;

  bf16x8 qf[4];
#pragma unroll
  for (int kd = 0; kd < 4; kd++) {
    int row = q0 + w * 16 + lr;
    qf[kd] = *(const bf16x8*)(q + kvbase + (size_t)row * DHD + kd * 32 + lk * 8);
  }

  f32x4 zero = {0.f, 0.f, 0.f, 0.f};
  f32x4 acc[8];
#pragma unroll
  for (int ni = 0; ni < 8; ni++) acc[ni] = zero;
  float mrow[4], lsum[4];
#pragma unroll
  for (int r = 0; r < 4; r++) {
    mrow[r] = -1e38f;
    lsum[r] = 0.f;
  }

  for (int kt = 0; kt <= qt; ++kt) {
    // stage K tile 64x128 (16KB) and V^T tile 128x64 (16KB)
#pragma unroll
    for (int p = 0; p < 4; ++p) {
      int c = p * 256 + tid;
      int kp = c >> 4, sl = c & 15;
      int sls = sl ^ (kp & 7);
      gl16(k + kvbase + (size_t)(kt * 64 + kp) * DHD + sls * 8, (char*)sK + c * 16);
    }
#pragma unroll
    for (int p = 0; p < 4; ++p) {
      int c = p * 256 + tid;
      int dh = c >> 3, sl = c & 7;
      int sls = sl ^ (dh & 7);
      gl16(vt + ((size_t)bh * DHD + dh) * S_LEN + kt * 64 + sls * 8, (char*)sV + c * 16);
    }
    __syncthreads();

    // QK^T: 16 q-rows x 64 k-cols per wave
    f32x4 sf[4];
#pragma unroll
    for (int nk = 0; nk < 4; nk++) {
      f32x4 sacc = zero;
#pragma unroll
      for (int kd = 0; kd < 4; kd++) {
        int row = nk * 16 + lr;
        int off = row * 128 + (((kd * 4 + lk) ^ (row & 7)) * 8);
        bf16x8 kfrag = *(const bf16x8*)(sK + off);
        sacc = MFMA16(qf[kd], kfrag, sacc);
      }
      sf[nk] = sacc;
    }

    // online softmax (exp2 domain) + write P (bf16) to LDS
    const bool diag = (kt == qt);
#pragma unroll
    for (int r = 0; r < 4; r++) {
      int qpos = q0 + w * 16 + lk * 4 + r;
      float lg[4];
      float mx = -3e38f;
#pragma unroll
      for (int nk = 0; nk < 4; nk++) {
        int kpos = kt * 64 + nk * 16 + lr;
        float vsc = sf[nk][r] * SCALE_L2E;
        if (diag && kpos > qpos) vsc = -3e38f;
        lg[nk] = vsc;
        mx = fmaxf(mx, vsc);
      }
#pragma unroll
      for (int d = 1; d < 16; d <<= 1) mx = fmaxf(mx, __shfl_xor(mx, d));
      float mnew = fmaxf(mrow[r], mx);
      float corr = exp2f(mrow[r] - mnew);
      float ps = 0.f;
      unsigned short pb[4];
#pragma unroll
      for (int nk = 0; nk < 4; nk++) {
        float p = exp2f(lg[nk] - mnew);
        ps += p;
        pb[nk] = f2bf(p);
      }
#pragma unroll
      for (int d = 1; d < 16; d <<= 1) ps += __shfl_xor(ps, d);
      lsum[r] = lsum[r] * corr + ps;
      mrow[r] = mnew;
#pragma unroll
      for (int ni = 0; ni < 8; ni++) acc[ni][r] *= corr;
      int prow = w * 16 + lk * 4 + r;
#pragma unroll
      for (int nk = 0; nk < 4; nk++) sP[prow * 72 + nk * 16 + lr] = pb[nk];
    }
    __syncthreads();

    // PV: O += P @ V
    bf16x8 pa[2];
#pragma unroll
    for (int ks = 0; ks < 2; ks++) {
      int row = w * 16 + lr;
      pa[ks] = *(const bf16x8*)(sP + row * 72 + ks * 32 + lk * 8);
    }
#pragma unroll
    for (int ni = 0; ni < 8; ni++) {
#pragma unroll
      for (int ks = 0; ks < 2; ks++) {
        int row = ni * 16 + lr;
        int off = row * 64 + (((ks * 4 + lk) ^ (row & 7)) * 8);
        bf16x8 vf = *(const bf16x8*)(sV + off);
        acc[ni] = MFMA16(pa[ks], vf, acc[ni]);
      }
    }
    __syncthreads();
  }

  // normalize + store O as bf16 into [B][S][H*Dh]
#pragma unroll
  for (int r = 0; r < 4; r++) {
    float inv = 1.0f / lsum[r];
    int srow = q0 + w * 16 + lk * 4 + r;
    size_t base = ((size_t)b * S_LEN + srow) * DMODEL + h * DHD;
#pragma unroll
    for (int ni = 0; ni < 8; ni++) o[base + ni * 16 + lr] = f2bf(acc[ni][r] * inv);
  }
}

// ---------------- tile scoring + top-8 (exact ranking, fp32) ----------------
__global__ __launch_bounds__(256) void k_score(const float* __restrict__ x,
                                               const float* __restrict__ wq,
                                               const float* __restrict__ cosT,
                                               const float* __restrict__ sinT,
                                               const float* __restrict__ kf,
                                               float* __restrict__ idxout) {
  const int t = blockIdx.x, bh = blockIdx.y;
  const int b = bh >> 4, h = bh & 15;
  const int srep = t * 128 + 127;
  const int tid = threadIdx.x;
  __shared__ float qr[128];
  __shared__ float part[256];
  __shared__ unsigned keys[16];

  {
    const int dh = tid & 127, half = tid >> 7;
    const float* xrow = x + ((size_t)b * S_LEN + srep) * DMODEL;
    const float* wcol = wq + (size_t)h * DHD + dh;
    float s0 = 0.f, s1 = 0.f, s2 = 0.f, s3 = 0.f;
    const int dbase = half * 1024;
    for (int d = 0; d < 1024; d += 4) {
      int dd = dbase + d;
      s0 = fmaf(xrow[dd], wcol[(size_t)dd * DMODEL], s0);
      s1 = fmaf(xrow[dd + 1], wcol[(size_t)(dd + 1) * DMODEL], s1);
      s2 = fmaf(xrow[dd + 2], wcol[(size_t)(dd + 2) * DMODEL], s2);
      s3 = fmaf(xrow[dd + 3], wcol[(size_t)(dd + 3) * DMODEL], s3);
    }
    part[tid] = (s0 + s1) + (s2 + s3);
  }
  if (tid < 16) keys[tid] = ~__float_as_uint(NEG10);
  __syncthreads();
  if (tid < 64) {
    int i = tid;
    float q0v = part[i] + part[i + 128];
    float q1v = part[i + 64] + part[i + 192];
    float c = cosT[(size_t)srep * 64 + i], sn = sinT[(size_t)srep * 64 + i];
    qr[i] = q0v * c - q1v * sn;
    qr[i + 64] = q1v * c + q0v * sn;
  }
  __syncthreads();

  for (int j = tid; j <= srep; j += 256) {
    const float4* krow = (const float4*)(kf + ((size_t)bh * S_LEN + j) * DHD);
    float a0 = 0.f, a1 = 0.f, a2 = 0.f, a3 = 0.f;
#pragma unroll 8
    for (int d4 = 0; d4 < 32; d4++) {
      float4 kv = krow[d4];
      const float* qq = qr + d4 * 4;
      a0 = fmaf(kv.x, qq[0], a0);
      a1 = fmaf(kv.y, qq[1], a1);
      a2 = fmaf(kv.z, qq[2], a2);
      a3 = fmaf(kv.w, qq[3], a3);
    }
    float lg = ((a0 + a1) + (a2 + a3)) * SCALE;
    unsigned u = __float_as_uint(lg);
    unsigned key = (u & 0x80000000u) ? ~u : (u | 0x80000000u);
    atomicMax(&keys[j >> 7], key);
  }
  __syncthreads();

  if (tid == 0) {
    unsigned used = 0;
    float* dst = idxout + ((size_t)bh * 16 + t) * 8;
    for (int r = 0; r < 8; ++r) {
      int best = -1;
      unsigned bk = 0;
#pragma unroll
      for (int tl = 0; tl < 16; ++tl) {
        if (used & (1u << tl)) continue;
        unsigned kv = keys[tl];
        if (best < 0 || kv > bk) {
          bk = kv;
          best = tl;
        }
      }
      used |= (1u << best);
      dst[r] = (float)best;
    }
  }
}

// ---------------------------------------------------------------------------
extern "C" void kernel_launch(void* const* d_in, const int* in_sizes, int n_in,
                              void* d_out, int out_size, void* d_ws, size_t ws_size,
                              hipStream_t stream) {
  (void)in_sizes; (void)n_in; (void)out_size; (void)ws_size;
  const float* x = (const float*)d_in[0];
  const float* wq = (const float*)d_in[1];
  const float* wk = (const float*)d_in[2];
  const float* wv = (const float*)d_in[3];
  const float* wo = (const float*)d_in[4];
  const float* cosT = (const float*)d_in[5];
  const float* sinT = (const float*)d_in[6];
  float* out0 = (float*)d_out;                       // [2,2048,2048] fp32
  float* out1 = out0 + (size_t)MROWS * DMODEL;       // [2,16,16,8] indices as float
  float* kf32 = out0;                                // reuse out0 as k_f32 scratch!

  char* ws = (char*)d_ws;
  size_t off = 0;
  auto alloc = [&](size_t bytes) {
    void* p = ws + off;
    off += (bytes + 255) & ~(size_t)255;
    return p;
  };
  unsigned short* xh = (unsigned short*)alloc(16777216);
  unsigned short* xl = (unsigned short*)alloc(16777216);
  unsigned short* wqT = (unsigned short*)alloc(8388608);
  unsigned short* wkT = (unsigned short*)alloc(8388608);
  unsigned short* wkTl = (unsigned short*)alloc(8388608);
  unsigned short* wvT = (unsigned short*)alloc(8388608);
  unsigned short* woT = (unsigned short*)alloc(8388608);
  unsigned short* qbf = (unsigned short*)alloc(16777216);
  unsigned short* kbf = (unsigned short*)alloc(16777216);
  unsigned short* vbf = (unsigned short*)alloc(16777216);
  // alias dead regions: obf<-xh (xh dead after proj GEMMs), vtbf<-xl
  unsigned short* obf = xh;
  unsigned short* vtbf = xl;

  k_split_x<<<2048, 256, 0, stream>>>(x, xh, xl, MROWS * DMODEL / 4);
  dim3 gtw(8, 64);
  k_transw<0><<<gtw, 256, 0, stream>>>(wq, wqT, nullptr);
  k_transw<1><<<gtw, 256, 0, stream>>>(wk, wkT, wkTl);
  k_transw<0><<<gtw, 256, 0, stream>>>(wv, wvT, nullptr);
  k_transw<0><<<gtw, 256, 0, stream>>>(wo, woT, nullptr);

  dim3 gg(16, 32);
  k_gemm<0, 0><<<gg, 256, 0, stream>>>(xh, nullptr, wqT, nullptr, qbf);
  k_gemm<1, 1><<<gg, 256, 0, stream>>>(xh, xl, wkT, wkTl, kf32);   // fp32-grade k
  k_gemm<0, 0><<<gg, 256, 0, stream>>>(xh, nullptr, wvT, nullptr, vbf);

  k_rope_q<<<4096, 256, 0, stream>>>(qbf, cosT, sinT);
  k_rope_k<<<4096, 256, 0, stream>>>(kf32, kbf, cosT, sinT);

  k_vtrans<<<dim3(32, 32), 256, 0, stream>>>(vbf, vtbf);
  k_attn<<<dim3(32, 32), 256, 0, stream>>>(qbf, kbf, vtbf, obf);

  // scoring must run BEFORE the final GEMM overwrites kf32 (== out0)
  k_score<<<dim3(16, 32), 256, 0, stream>>>(x, wq, cosT, sinT, kf32, out1);

  k_gemm<0, 2><<<gg, 256, 0, stream>>>(obf, nullptr, woT, nullptr, out0);
}

// Round 6
// 685.117 us; speedup vs baseline: 1.1408x; 1.0223x over previous
//
#include <hip/hip_runtime.h>
#include <cstdint>
#include <cstddef>

// ---------------------------------------------------------------------------
// KascadeAnchorAttention: x->QKV proj (+RoPE) -> causal attn -> out proj,
// plus top-8 tile indices from rep-row logits.
// B=2 H=16 S=2048 Dh=128 D=2048. TILE=128 TOPK=8.
//
// R4 -> R5 (attention only):
//  - paired q-tiles (p, 31-p) in one k-loop, K/V staged once per kt
//  - XCD-chunked block swizzle (same-bh blocks share an XCD L2)
//  - per-lane lsum partials (single end reduce), defer-rescale (exact),
//    native __bf16 casts for P, __launch_bounds__(256,2)
// ---------------------------------------------------------------------------

#define S_LEN 2048
#define NH 16
#define DHD 128
#define DMODEL 2048
#define MROWS 4096
#define SCALE 0.08838834764831845f   // 1/sqrt(128)
#define SCALE_L2E (0.08838834764831845f * 1.4426950408889634f)
#define NEG10 -1e10f

typedef short short8 __attribute__((ext_vector_type(8)));
typedef __bf16 bf16x8 __attribute__((ext_vector_type(8)));
typedef float f32x4 __attribute__((ext_vector_type(4)));

#define MFMA16(a, b, c) __builtin_amdgcn_mfma_f32_16x16x32_bf16((a), (b), (c), 0, 0, 0)

__device__ __forceinline__ void gl16(const void* g, void* s) {
  __builtin_amdgcn_global_load_lds(
      (const __attribute__((address_space(1))) void*)g,
      (__attribute__((address_space(3))) void*)s, 16, 0, 0);
}

__device__ __forceinline__ unsigned short f2bf(float f) {
  unsigned u = __float_as_uint(f);
  return (unsigned short)((u + 0x7fffu + ((u >> 16) & 1u)) >> 16);  // RNE
}
__device__ __forceinline__ float bf2f(unsigned short h) {
  return __uint_as_float(((unsigned)h) << 16);
}

// ---------------- split x into bf16 hi/lo ----------------
__global__ __launch_bounds__(256) void k_split_x(const float* __restrict__ x,
                                                 unsigned short* __restrict__ xh,
                                                 unsigned short* __restrict__ xl, int n4) {
  int i = blockIdx.x * blockDim.x + threadIdx.x;
  for (; i < n4; i += gridDim.x * blockDim.x) {
    float4 v = ((const float4*)x)[i];
    float f[4] = {v.x, v.y, v.z, v.w};
    unsigned short hh[4], ll[4];
#pragma unroll
    for (int j = 0; j < 4; j++) {
      hh[j] = f2bf(f[j]);
      ll[j] = f2bf(f[j] - bf2f(hh[j]));
    }
    ((ushort4*)xh)[i] = make_ushort4(hh[0], hh[1], hh[2], hh[3]);
    ((ushort4*)xl)[i] = make_ushort4(ll[0], ll[1], ll[2], ll[3]);
  }
}

// ---------------- transpose weight [K][N] -> [N][K] bf16 (hi, optional lo) ---
template <int LO>
__global__ __launch_bounds__(256) void k_transw(const float* __restrict__ w,
                                                unsigned short* __restrict__ th,
                                                unsigned short* __restrict__ tl) {
  int n = blockIdx.x * 256 + threadIdx.x;
  int r0 = blockIdx.y * 32;
  float vals[32];
#pragma unroll
  for (int j = 0; j < 32; j++) vals[j] = w[(size_t)(r0 + j) * DMODEL + n];
  unsigned short hs[32];
#pragma unroll
  for (int j = 0; j < 32; j++) hs[j] = f2bf(vals[j]);
  unsigned short* dsth = th + (size_t)n * DMODEL + r0;
#pragma unroll
  for (int c = 0; c < 4; c++) {
    short8 v;
#pragma unroll
    for (int j = 0; j < 8; j++) v[j] = (short)hs[c * 8 + j];
    *(short8*)(dsth + c * 8) = v;
  }
  if (LO) {
    unsigned short ls[32];
#pragma unroll
    for (int j = 0; j < 32; j++) ls[j] = f2bf(vals[j] - bf2f(hs[j]));
    unsigned short* dstl = tl + (size_t)n * DMODEL + r0;
#pragma unroll
    for (int c = 0; c < 4; c++) {
      short8 v;
#pragma unroll
      for (int j = 0; j < 8; j++) v[j] = (short)ls[c * 8 + j];
      *(short8*)(dstl + c * 8) = v;
    }
  }
}

// ---------------- 128x128 MFMA GEMM, BK=32, optional bf16x2 split ----------
template <int SPLIT, int EPI>
__global__ __launch_bounds__(256) void k_gemm(const unsigned short* __restrict__ A,
                                              const unsigned short* __restrict__ Al,
                                              const unsigned short* __restrict__ Bt,
                                              const unsigned short* __restrict__ Btl,
                                              void* __restrict__ outp) {
  constexpr int NSM = (SPLIT ? 4 : 2) * 4096;
  __shared__ unsigned short sm[NSM];
  unsigned short* sAh = sm;
  unsigned short* sAl = SPLIT ? (sm + 4096) : nullptr;
  unsigned short* sBh = sm + (SPLIT ? 8192 : 4096);
  unsigned short* sBl = SPLIT ? (sm + 12288) : nullptr;

  const int tid = threadIdx.x;
  const int l = tid & 63, w = tid >> 6;
  const int lr = l & 15, lk = l >> 4;
  const int rowBase = blockIdx.y * 128;
  const int colBase = blockIdx.x * 128;
  const int wr = (w >> 1) * 64, wc = (w & 1) * 64;

  f32x4 zero = {0.f, 0.f, 0.f, 0.f};
  f32x4 acc[4][4];
#pragma unroll
  for (int mi = 0; mi < 4; mi++)
#pragma unroll
    for (int ni = 0; ni < 4; ni++) acc[mi][ni] = zero;

  for (int kt = 0; kt < 64; ++kt) {
#pragma unroll
    for (int p = 0; p < 2; ++p) {
      int c = w * 128 + p * 64 + l;
      int row = c >> 2, sl = c & 3;
      int kbl = sl ^ ((row >> 1) & 3);
      size_t srca = (size_t)(rowBase + row) * DMODEL + kt * 32 + kbl * 8;
      gl16(A + srca, (char*)sAh + c * 16);
      if (SPLIT) gl16(Al + srca, (char*)sAl + c * 16);
      size_t srcb = (size_t)(colBase + row) * DMODEL + kt * 32 + kbl * 8;
      gl16(Bt + srcb, (char*)sBh + c * 16);
      if (SPLIT) gl16(Btl + srcb, (char*)sBl + c * 16);
    }
    __syncthreads();

    bf16x8 ah[4], alo[4], bh[4], blo[4];
#pragma unroll
    for (int mi = 0; mi < 4; mi++) {
      int row = wr + mi * 16 + lr;
      int off = row * 32 + ((lk ^ ((row >> 1) & 3)) * 8);
      ah[mi] = *(const bf16x8*)(sAh + off);
      if (SPLIT) alo[mi] = *(const bf16x8*)(sAl + off);
    }
#pragma unroll
    for (int ni = 0; ni < 4; ni++) {
      int row = wc + ni * 16 + lr;
      int off = row * 32 + ((lk ^ ((row >> 1) & 3)) * 8);
      bh[ni] = *(const bf16x8*)(sBh + off);
      if (SPLIT) blo[ni] = *(const bf16x8*)(sBl + off);
    }
#pragma unroll
    for (int mi = 0; mi < 4; mi++)
#pragma unroll
      for (int ni = 0; ni < 4; ni++) {
        acc[mi][ni] = MFMA16(ah[mi], bh[ni], acc[mi][ni]);
        if (SPLIT) {
          acc[mi][ni] = MFMA16(alo[mi], bh[ni], acc[mi][ni]);
          acc[mi][ni] = MFMA16(ah[mi], blo[ni], acc[mi][ni]);
        }
      }
    __syncthreads();
  }

#pragma unroll
  for (int mi = 0; mi < 4; mi++)
#pragma unroll
    for (int ni = 0; ni < 4; ni++)
#pragma unroll
      for (int r = 0; r < 4; r++) {
        int row = rowBase + wr + mi * 16 + lk * 4 + r;
        int col = colBase + wc + ni * 16 + lr;
        float v = acc[mi][ni][r];
        if (EPI == 2) {
          ((float*)outp)[(size_t)row * DMODEL + col] = v;
        } else {
          size_t idx = (((size_t)(row >> 11) * NH + (col >> 7)) * S_LEN + (row & 2047)) * DHD +
                       (col & 127);
          if (EPI == 1)
            ((float*)outp)[idx] = v;
          else
            ((unsigned short*)outp)[idx] = f2bf(v);
        }
      }
}

// ---------------- RoPE, half-split form -------------------------------------
__global__ __launch_bounds__(256) void k_rope_q(unsigned short* __restrict__ q,
                                                const float* __restrict__ cosT,
                                                const float* __restrict__ sinT) {
  int t = blockIdx.x * blockDim.x + threadIdx.x;
  int row = t >> 4;
  int i4 = (t & 15) * 4;
  int s = row & 2047;
  unsigned short* p0 = q + (size_t)row * DHD + i4;
  unsigned short* p1 = p0 + 64;
  ushort4 a = *(ushort4*)p0, b = *(ushort4*)p1;
  float4 c = *(const float4*)(cosT + (size_t)s * 64 + i4);
  float4 sn = *(const float4*)(sinT + (size_t)s * 64 + i4);
  float av[4] = {bf2f(a.x), bf2f(a.y), bf2f(a.z), bf2f(a.w)};
  float bv[4] = {bf2f(b.x), bf2f(b.y), bf2f(b.z), bf2f(b.w)};
  float cv[4] = {c.x, c.y, c.z, c.w}, sv[4] = {sn.x, sn.y, sn.z, sn.w};
  unsigned short na[4], nb[4];
#pragma unroll
  for (int j = 0; j < 4; j++) {
    na[j] = f2bf(av[j] * cv[j] - bv[j] * sv[j]);
    nb[j] = f2bf(bv[j] * cv[j] + av[j] * sv[j]);
  }
  *(ushort4*)p0 = make_ushort4(na[0], na[1], na[2], na[3]);
  *(ushort4*)p1 = make_ushort4(nb[0], nb[1], nb[2], nb[3]);
}

__global__ __launch_bounds__(256) void k_rope_k(float* __restrict__ kf,
                                                unsigned short* __restrict__ kb,
                                                const float* __restrict__ cosT,
                                                const float* __restrict__ sinT) {
  int t = blockIdx.x * blockDim.x + threadIdx.x;
  int row = t >> 4;
  int i4 = (t & 15) * 4;
  int s = row & 2047;
  float* p0 = kf + (size_t)row * DHD + i4;
  float* p1 = p0 + 64;
  float4 a = *(float4*)p0, b = *(float4*)p1;
  float4 c = *(const float4*)(cosT + (size_t)s * 64 + i4);
  float4 sn = *(const float4*)(sinT + (size_t)s * 64 + i4);
  float av[4] = {a.x, a.y, a.z, a.w}, bv[4] = {b.x, b.y, b.z, b.w};
  float cv[4] = {c.x, c.y, c.z, c.w}, sv[4] = {sn.x, sn.y, sn.z, sn.w};
  float na[4], nb[4];
#pragma unroll
  for (int j = 0; j < 4; j++) {
    na[j] = av[j] * cv[j] - bv[j] * sv[j];
    nb[j] = bv[j] * cv[j] + av[j] * sv[j];
  }
  *(float4*)p0 = make_float4(na[0], na[1], na[2], na[3]);
  *(float4*)p1 = make_float4(nb[0], nb[1], nb[2], nb[3]);
  unsigned short* kb0 = kb + (size_t)row * DHD + i4;
  *(ushort4*)kb0 = make_ushort4(f2bf(na[0]), f2bf(na[1]), f2bf(na[2]), f2bf(na[3]));
  *(ushort4*)(kb0 + 64) = make_ushort4(f2bf(nb[0]), f2bf(nb[1]), f2bf(nb[2]), f2bf(nb[3]));
}

// ---------------- V transpose: [bh][S][Dh] -> [bh][Dh][S] bf16 --------------
__global__ __launch_bounds__(256) void k_vtrans(const unsigned short* __restrict__ v,
                                                unsigned short* __restrict__ vt) {
  int bh = blockIdx.y;
  int s0 = blockIdx.x * 64 + (threadIdx.x >> 7) * 32;
  int d = threadIdx.x & 127;
  unsigned short tmp[32];
#pragma unroll
  for (int j = 0; j < 32; j++) tmp[j] = v[((size_t)bh * S_LEN + s0 + j) * DHD + d];
  unsigned short* dst = vt + ((size_t)bh * DHD + d) * S_LEN + s0;
#pragma unroll
  for (int c = 0; c < 4; c++) {
    short8 x;
#pragma unroll
    for (int j = 0; j < 8; j++) x[j] = (short)tmp[c * 8 + j];
    *(short8*)(dst + c * 8) = x;
  }
}

// ---------------- flash attention helpers -----------------------------------
__device__ __forceinline__ void attn_qk_sm(const bf16x8 (&qf)[4], f32x4 (&acc)[8],
                                           float (&mrow)[4], float (&lsum)[4],
                                           const unsigned short* sK, __bf16* sP,
                                           int ktbase, bool diag, int q0, int w, int lr,
                                           int lk) {
  f32x4 zero = {0.f, 0.f, 0.f, 0.f};
  f32x4 sf[4];
#pragma unroll
  for (int nk = 0; nk < 4; nk++) {
    f32x4 sacc = zero;
#pragma unroll
    for (int kd = 0; kd < 4; kd++) {
      int row = nk * 16 + lr;
      int off = row * 128 + (((kd * 4 + lk) ^ (row & 7)) * 8);
      bf16x8 kfrag = *(const bf16x8*)(sK + off);
      sacc = MFMA16(qf[kd], kfrag, sacc);
    }
    sf[nk] = sacc;
  }
#pragma unroll
  for (int r = 0; r < 4; r++) {
    int qpos = q0 + w * 16 + lk * 4 + r;
    float lg[4];
    float mx = -3e38f;
#pragma unroll
    for (int nk = 0; nk < 4; nk++) {
      int kpos = ktbase + nk * 16 + lr;
      float vsc = sf[nk][r] * SCALE_L2E;
      if (diag && kpos > qpos) vsc = -3e38f;
      lg[nk] = vsc;
      mx = fmaxf(mx, vsc);
    }
#pragma unroll
    for (int d = 1; d < 16; d <<= 1) mx = fmaxf(mx, __shfl_xor(mx, d));
    if (mx > mrow[r]) {  // defer-rescale: exact (corr==1 path skipped entirely)
      float corr = exp2f(mrow[r] - mx);
      mrow[r] = mx;
      lsum[r] *= corr;
#pragma unroll
      for (int ni = 0; ni < 8; ni++) acc[ni][r] *= corr;
    }
    float m = mrow[r];
    float ps = 0.f;
    int prow = w * 16 + lk * 4 + r;
#pragma unroll
    for (int nk = 0; nk < 4; nk++) {
      float pv = exp2f(lg[nk] - m);
      ps += pv;
      sP[prow * 72 + nk * 16 + lr] = (__bf16)pv;
    }
    lsum[r] += ps;  // per-lane partial; reduced once at the end
  }
}

__device__ __forceinline__ void attn_pv(f32x4 (&acc)[8], const __bf16* sP,
                                        const unsigned short* sV, int w, int lr, int lk) {
  bf16x8 pa[2];
#pragma unroll
  for (int ks = 0; ks < 2; ks++) {
    int row = w * 16 + lr;
    pa[ks] = *(const bf16x8*)(sP + row * 72 + ks * 32 + lk * 8);
  }
#pragma unroll
  for (int ni = 0; ni < 8; ni++) {
#pragma unroll
    for (int ks = 0; ks < 2; ks++) {
      int row = ni * 16 + lr;
      int off = row * 64 + (((ks * 4 + lk) ^ (row & 7)) * 8);
      bf16x8 vf = *(const bf16x8*)(sV + off);
      acc[ni] = MFMA16(pa[ks], vf, acc[ni]);
    }
  }
}

// ---------------- flash attention (causal), paired q-tiles -------------------
// 512 blocks; block handles q-tiles p and 31-p in ONE k-loop (shared staging).
// XCD-chunk swizzle groups same-bh blocks on one XCD for K/V L2 reuse.
__global__ __launch_bounds__(256, 2) void k_attn(const unsigned short* __restrict__ q,
                                                 const unsigned short* __restrict__ k,
                                                 const unsigned short* __restrict__ vt,
                                                 unsigned short* __restrict__ o) {
  __shared__ unsigned short sK[64 * 128];  // [kp][d], 16B-slot ^= (kp&7)
  __shared__ unsigned short sV[128 * 64];  // [dh][kp], 16B-slot ^= (dh&7)
  __shared__ __bf16 sPA[64 * 72];
  __shared__ __bf16 sPB[64 * 72];

  const int bid = blockIdx.x;
  const int workid = (bid & 7) * 64 + (bid >> 3);  // nwg=512, 512%8==0 -> bijective
  const int bh = workid >> 4, p = workid & 15;
  const int qtA = p, qtB = 31 - p;
  const int b = bh >> 4, h = bh & 15;
  const int tid = threadIdx.x, l = tid & 63, w = tid >> 6;
  const int lr = l & 15, lk = l >> 4;
  const int q0A = qtA * 64, q0B = qtB * 64;
  const size_t kvbase = (size_t)bh * S_LEN * DHD;

  bf16x8 qfA[4], qfB[4];
#pragma unroll
  for (int kd = 0; kd < 4; kd++) {
    qfA[kd] = *(const bf16x8*)(q + kvbase + (size_t)(q0A + w * 16 + lr) * DHD + kd * 32 + lk * 8);
    qfB[kd] = *(const bf16x8*)(q + kvbase + (size_t)(q0B + w * 16 + lr) * DHD + kd * 32 + lk * 8);
  }

  f32x4 zero = {0.f, 0.f, 0.f, 0.f};
  f32x4 accA[8], accB[8];
  float mrowA[4], lsumA[4], mrowB[4], lsumB[4];
#pragma unroll
  for (int ni = 0; ni < 8; ni++) { accA[ni] = zero; accB[ni] = zero; }
#pragma unroll
  for (int r = 0; r < 4; r++) {
    mrowA[r] = -3e38f; lsumA[r] = 0.f;
    mrowB[r] = -3e38f; lsumB[r] = 0.f;
  }

  for (int kt = 0; kt <= qtB; ++kt) {
    // stage K tile 64x128 (16KB) and V^T tile 128x64 (16KB), once for both segs
#pragma unroll
    for (int pp = 0; pp < 4; ++pp) {
      int c = pp * 256 + tid;
      int kp = c >> 4, sl = c & 15;
      int sls = sl ^ (kp & 7);
      gl16(k + kvbase + (size_t)(kt * 64 + kp) * DHD + sls * 8, (char*)sK + c * 16);
    }
#pragma unroll
    for (int pp = 0; pp < 4; ++pp) {
      int c = pp * 256 + tid;
      int dh = c >> 3, sl = c & 7;
      int sls = sl ^ (dh & 7);
      gl16(vt + ((size_t)bh * DHD + dh) * S_LEN + kt * 64 + sls * 8, (char*)sV + c * 16);
    }
    __syncthreads();

    const bool doA = (kt <= qtA);
    attn_qk_sm(qfB, accB, mrowB, lsumB, sK, sPB, kt * 64, kt == qtB, q0B, w, lr, lk);
    if (doA)
      attn_qk_sm(qfA, accA, mrowA, lsumA, sK, sPA, kt * 64, kt == qtA, q0A, w, lr, lk);
    __syncthreads();

    attn_pv(accB, sPB, sV, w, lr, lk);
    if (doA) attn_pv(accA, sPA, sV, w, lr, lk);
    __syncthreads();
  }

  // final lsum reduce (deferred from per-iter) + store O
#pragma unroll
  for (int r = 0; r < 4; r++) {
#pragma unroll
    for (int d = 1; d < 16; d <<= 1) {
      lsumA[r] += __shfl_xor(lsumA[r], d);
      lsumB[r] += __shfl_xor(lsumB[r], d);
    }
  }
#pragma unroll
  for (int r = 0; r < 4; r++) {
    float invA = 1.0f / lsumA[r], invB = 1.0f / lsumB[r];
    int srowA = q0A + w * 16 + lk * 4 + r;
    int srowB = q0B + w * 16 + lk * 4 + r;
    size_t baseA = ((size_t)b * S_LEN + srowA) * DMODEL + h * DHD;
    size_t baseB = ((size_t)b * S_LEN + srowB) * DMODEL + h * DHD;
#pragma unroll
    for (int ni = 0; ni < 8; ni++) {
      o[baseA + ni * 16 + lr] = f2bf(accA[ni][r] * invA);
      o[baseB + ni * 16 + lr] = f2bf(accB[ni][r] * invB);
    }
  }
}

// ---------------- tile scoring + top-8 (exact ranking, fp32) ----------------
__global__ __launch_bounds__(256) void k_score(const float* __restrict__ x,
                                               const float* __restrict__ wq,
                                               const float* __restrict__ cosT,
                                               const float* __restrict__ sinT,
                                               const float* __restrict__ kf,
                                               float* __restrict__ idxout) {
  const int t = blockIdx.x, bh = blockIdx.y;
  const int b = bh >> 4, h = bh & 15;
  const int srep = t * 128 + 127;
  const int tid = threadIdx.x;
  __shared__ float qr[128];
  __shared__ float part[256];
  __shared__ unsigned keys[16];

  {
    const int dh = tid & 127, half = tid >> 7;
    const float* xrow = x + ((size_t)b * S_LEN + srep) * DMODEL;
    const float* wcol = wq + (size_t)h * DHD + dh;
    float s0 = 0.f, s1 = 0.f, s2 = 0.f, s3 = 0.f;
    const int dbase = half * 1024;
    for (int d = 0; d < 1024; d += 4) {
      int dd = dbase + d;
      s0 = fmaf(xrow[dd], wcol[(size_t)dd * DMODEL], s0);
      s1 = fmaf(xrow[dd + 1], wcol[(size_t)(dd + 1) * DMODEL], s1);
      s2 = fmaf(xrow[dd + 2], wcol[(size_t)(dd + 2) * DMODEL], s2);
      s3 = fmaf(xrow[dd + 3], wcol[(size_t)(dd + 3) * DMODEL], s3);
    }
    part[tid] = (s0 + s1) + (s2 + s3);
  }
  if (tid < 16) keys[tid] = ~__float_as_uint(NEG10);
  __syncthreads();
  if (tid < 64) {
    int i = tid;
    float q0v = part[i] + part[i + 128];
    float q1v = part[i + 64] + part[i + 192];
    float c = cosT[(size_t)srep * 64 + i], sn = sinT[(size_t)srep * 64 + i];
    qr[i] = q0v * c - q1v * sn;
    qr[i + 64] = q1v * c + q0v * sn;
  }
  __syncthreads();

  for (int j = tid; j <= srep; j += 256) {
    const float4* krow = (const float4*)(kf + ((size_t)bh * S_LEN + j) * DHD);
    float a0 = 0.f, a1 = 0.f, a2 = 0.f, a3 = 0.f;
#pragma unroll 8
    for (int d4 = 0; d4 < 32; d4++) {
      float4 kv = krow[d4];
      const float* qq = qr + d4 * 4;
      a0 = fmaf(kv.x, qq[0], a0);
      a1 = fmaf(kv.y, qq[1], a1);
      a2 = fmaf(kv.z, qq[2], a2);
      a3 = fmaf(kv.w, qq[3], a3);
    }
    float lg = ((a0 + a1) + (a2 + a3)) * SCALE;
    unsigned u = __float_as_uint(lg);
    unsigned key = (u & 0x80000000u) ? ~u : (u | 0x80000000u);
    atomicMax(&keys[j >> 7], key);
  }
  __syncthreads();

  if (tid == 0) {
    unsigned used = 0;
    float* dst = idxout + ((size_t)bh * 16 + t) * 8;
    for (int r = 0; r < 8; ++r) {
      int best = -1;
      unsigned bk = 0;
#pragma unroll
      for (int tl = 0; tl < 16; ++tl) {
        if (used & (1u << tl)) continue;
        unsigned kv = keys[tl];
        if (best < 0 || kv > bk) {
          bk = kv;
          best = tl;
        }
      }
      used |= (1u << best);
      dst[r] = (float)best;
    }
  }
}

// ---------------------------------------------------------------------------
extern "C" void kernel_launch(void* const* d_in, const int* in_sizes, int n_in,
                              void* d_out, int out_size, void* d_ws, size_t ws_size,
                              hipStream_t stream) {
  (void)in_sizes; (void)n_in; (void)out_size; (void)ws_size;
  const float* x = (const float*)d_in[0];
  const float* wq = (const float*)d_in[1];
  const float* wk = (const float*)d_in[2];
  const float* wv = (const float*)d_in[3];
  const float* wo = (const float*)d_in[4];
  const float* cosT = (const float*)d_in[5];
  const float* sinT = (const float*)d_in[6];
  float* out0 = (float*)d_out;                       // [2,2048,2048] fp32
  float* out1 = out0 + (size_t)MROWS * DMODEL;       // [2,16,16,8] indices as float
  float* kf32 = out0;                                // reuse out0 as k_f32 scratch!

  char* ws = (char*)d_ws;
  size_t off = 0;
  auto alloc = [&](size_t bytes) {
    void* p = ws + off;
    off += (bytes + 255) & ~(size_t)255;
    return p;
  };
  unsigned short* xh = (unsigned short*)alloc(16777216);
  unsigned short* xl = (unsigned short*)alloc(16777216);
  unsigned short* wqT = (unsigned short*)alloc(8388608);
  unsigned short* wkT = (unsigned short*)alloc(8388608);
  unsigned short* wkTl = (unsigned short*)alloc(8388608);
  unsigned short* wvT = (unsigned short*)alloc(8388608);
  unsigned short* woT = (unsigned short*)alloc(8388608);
  unsigned short* qbf = (unsigned short*)alloc(16777216);
  unsigned short* kbf = (unsigned short*)alloc(16777216);
  unsigned short* vbf = (unsigned short*)alloc(16777216);
  // alias dead regions: obf<-xh (xh dead after proj GEMMs), vtbf<-xl
  unsigned short* obf = xh;
  unsigned short* vtbf = xl;

  k_split_x<<<2048, 256, 0, stream>>>(x, xh, xl, MROWS * DMODEL / 4);
  dim3 gtw(8, 64);
  k_transw<0><<<gtw, 256, 0, stream>>>(wq, wqT, nullptr);
  k_transw<1><<<gtw, 256, 0, stream>>>(wk, wkT, wkTl);
  k_transw<0><<<gtw, 256, 0, stream>>>(wv, wvT, nullptr);
  k_transw<0><<<gtw, 256, 0, stream>>>(wo, woT, nullptr);

  dim3 gg(16, 32);
  k_gemm<0, 0><<<gg, 256, 0, stream>>>(xh, nullptr, wqT, nullptr, qbf);
  k_gemm<1, 1><<<gg, 256, 0, stream>>>(xh, xl, wkT, wkTl, kf32);   // fp32-grade k
  k_gemm<0, 0><<<gg, 256, 0, stream>>>(xh, nullptr, wvT, nullptr, vbf);

  k_rope_q<<<4096, 256, 0, stream>>>(qbf, cosT, sinT);
  k_rope_k<<<4096, 256, 0, stream>>>(kf32, kbf, cosT, sinT);

  k_vtrans<<<dim3(32, 32), 256, 0, stream>>>(vbf, vtbf);
  k_attn<<<512, 256, 0, stream>>>(qbf, kbf, vtbf, obf);

  // scoring must run BEFORE the final GEMM overwrites kf32 (== out0)
  k_score<<<dim3(16, 32), 256, 0, stream>>>(x, wq, cosT, sinT, kf32, out1);

  k_gemm<0, 2><<<gg, 256, 0, stream>>>(obf, nullptr, woT, nullptr, out0);
}